// Round 1
// baseline (1953.979 us; speedup 1.0000x reference)
//
#include <hip/hip_runtime.h>
#include <hip/hip_bf16.h>

#define NN 8192     // total nodes
#define CC 256      // nodes per graph == in_channels
#define BBg 32      // graphs
#define HH 128      // hidden
#define EE 131072   // edges

typedef __attribute__((ext_vector_type(8))) short short8;
typedef __attribute__((ext_vector_type(4))) float f32x4;

// Replicate fp32 hard_where(sigmoid(v)) boundary exactly:
// ref: s = 1/(1+exp(-v)) in fp32; out = (s <= 0.5) ? 0 : 1.
// For v<=0: exp(-v)>=1 -> s<=0.5 -> 0 always.
// For v>=1e-6: even with a 1-ulp-off exp, s > 0.5 -> 1 always.
// Middle zone (~never hit, but must be exact): correctly-rounded float exp
// via double, then IEEE fp32 add + div (hardware exact).
__device__ __forceinline__ float hard01(float v) {
    if (v >= 1e-6f) return 1.0f;
    if (v <= 0.0f) return 0.0f;
    float ef = (float)exp(-(double)v);
    float s = 1.0f / (1.0f + ef);
    return (s > 0.5f) ? 1.0f : 0.0f;
}

__device__ __forceinline__ unsigned short f2bf(float f) {
    unsigned u = __float_as_uint(f);
    u += 0x7FFFu + ((u >> 16) & 1u);   // RNE
    return (unsigned short)(u >> 16);
}
__device__ __forceinline__ float bf2f(unsigned short b) {
    return __uint_as_float(((unsigned)b) << 16);
}

// K1: adj scatter + per-(block,col) source-j lists
__global__ void k_scatter_build(const int* __restrict__ ei, float* __restrict__ adj,
                                int* __restrict__ colcnt, unsigned char* __restrict__ coljs) {
    int e = blockIdx.x * 256 + threadIdx.x;
    if (e >= EE) return;
    int r = ei[e], c = ei[EE + e];
    atomicAdd(&adj[(size_t)r * NN + c], 1.0f);
    int idx = (r >> 8) * NN + c;
    int slot = atomicAdd(&colcnt[idx], 1);
    if (slot < 16) coljs[(size_t)idx * 16 + slot] = (unsigned char)(r & 255);
}

// K2: M = hard01(mask_W[graph_id] rows), x_masked = M*x
__global__ void k_mask(const float* __restrict__ maskW, const int* __restrict__ gid,
                       const float* __restrict__ x, float* __restrict__ Mo,
                       float* __restrict__ xm) {
    int i = blockIdx.x * 256 + threadIdx.x;   // over N*C/4
    int base = i * 4;
    int r = base >> 8;
    int c = base & 255;
    int g = gid[r >> 8];
    float4 mv = *(const float4*)(maskW + ((size_t)g << 16) + ((size_t)(r & 255) << 8) + c);
    float4 xv = *(const float4*)(x + ((size_t)r << 8) + c);
    float4 m, o;
    m.x = hard01(mv.x); m.y = hard01(mv.y); m.z = hard01(mv.z); m.w = hard01(mv.w);
    o.x = m.x * xv.x; o.y = m.y * xv.y; o.z = m.z * xv.z; o.w = m.w * xv.w;
    *(float4*)(Mo + ((size_t)r << 8) + c) = m;
    *(float4*)(xm + ((size_t)r << 8) + c) = o;
}

// K3: pert_adj via sparse column lists; 32-row P tile in LDS; streams all 64M outputs
__global__ void __launch_bounds__(256) k_pertadj(const float* __restrict__ pertW,
                                                 const float* __restrict__ pertB,
                                                 const int* __restrict__ gid,
                                                 const int* __restrict__ colcnt,
                                                 const unsigned char* __restrict__ coljs,
                                                 float* __restrict__ padj) {
    __shared__ float Pl[32][257];
    int b = blockIdx.x >> 3, rt = blockIdx.x & 7;
    int t = threadIdx.x;
    int g = gid[b];
    const float* src = pertW + ((size_t)g << 16) + (size_t)rt * 32 * CC;
    #pragma unroll 4
    for (int i = 0; i < 32; ++i) Pl[i][t] = src[i * CC + t];
    __syncthreads();
    int lane = t & 63, rg = t >> 6;
    const float* bsrc = pertB + ((size_t)g << 16) + (size_t)rt * 32 * CC;
    for (int n0 = 0; n0 < NN; n0 += 64) {
        int n = n0 + lane;
        int cidx = b * NN + n;
        int cnt = colcnt[cidx];
        cnt = cnt > 16 ? 16 : cnt;
        uint4 jv = make_uint4(0, 0, 0, 0);
        if (cnt > 0) jv = *(const uint4*)(coljs + (size_t)cidx * 16);
        float s[8];
        #pragma unroll
        for (int ii = 0; ii < 8; ++ii) s[ii] = 0.0f;
        for (int q = 0; q < cnt; ++q) {
            unsigned word = (q < 8) ? ((q < 4) ? jv.x : jv.y) : ((q < 12) ? jv.z : jv.w);
            int j = (word >> ((q & 3) * 8)) & 255;
            #pragma unroll
            for (int ii = 0; ii < 8; ++ii) s[ii] += Pl[rg * 8 + ii][j];
        }
        bool diag = ((n >> 8) == b);
        #pragma unroll
        for (int ii = 0; ii < 8; ++ii) {
            int i = rg * 8 + ii;
            float v = s[ii];
            if (diag) v += bsrc[(size_t)i * CC + (n & 255)];
            padj[(size_t)(b * CC + rt * 32 + i) * NN + n] = hard01(v);
        }
    }
}

// K4: C[8192xK] -> out[8192x128]: out = relu?(A) @ W.
// Either writes fp32 Cout (pred path) or transposed bf16 hi/lo split Zt (aug path).
__global__ void __launch_bounds__(256) k_gemm(const float* __restrict__ A,
                                              const float* __restrict__ W,
                                              float* __restrict__ Cout,
                                              unsigned short* __restrict__ Zthi,
                                              unsigned short* __restrict__ Ztlo,
                                              int K, int relu) {
    __shared__ float Al[32][68];
    __shared__ float Wl[64][132];
    int mt = blockIdx.x;
    int t = threadIdx.x;
    int ty = t >> 3, tx = t & 7;
    float acc[16];
    #pragma unroll
    for (int u = 0; u < 16; ++u) acc[u] = 0.0f;
    for (int kc = 0; kc < K; kc += 64) {
        {
            int row = t >> 3, q = t & 7;
            const float* ap = A + (size_t)(mt * 32 + row) * K + kc + q * 8;
            float4 f0 = *(const float4*)ap;
            float4 f1 = *(const float4*)(ap + 4);
            if (relu) {
                f0.x = fmaxf(f0.x, 0.f); f0.y = fmaxf(f0.y, 0.f);
                f0.z = fmaxf(f0.z, 0.f); f0.w = fmaxf(f0.w, 0.f);
                f1.x = fmaxf(f1.x, 0.f); f1.y = fmaxf(f1.y, 0.f);
                f1.z = fmaxf(f1.z, 0.f); f1.w = fmaxf(f1.w, 0.f);
            }
            Al[row][q * 8 + 0] = f0.x; Al[row][q * 8 + 1] = f0.y;
            Al[row][q * 8 + 2] = f0.z; Al[row][q * 8 + 3] = f0.w;
            Al[row][q * 8 + 4] = f1.x; Al[row][q * 8 + 5] = f1.y;
            Al[row][q * 8 + 6] = f1.z; Al[row][q * 8 + 7] = f1.w;
        }
        {
            int row = t >> 2, q = t & 3;
            const float* wp = W + (size_t)(kc + row) * HH + q * 32;
            #pragma unroll
            for (int u = 0; u < 32; u += 4) {
                float4 f = *(const float4*)(wp + u);
                Wl[row][q * 32 + u + 0] = f.x; Wl[row][q * 32 + u + 1] = f.y;
                Wl[row][q * 32 + u + 2] = f.z; Wl[row][q * 32 + u + 3] = f.w;
            }
        }
        __syncthreads();
        #pragma unroll 4
        for (int kk = 0; kk < 64; ++kk) {
            float a = Al[ty][kk];
            #pragma unroll
            for (int u = 0; u < 16; u += 4) {
                float4 wv = *(const float4*)(&Wl[kk][tx * 16 + u]);
                acc[u + 0] += a * wv.x; acc[u + 1] += a * wv.y;
                acc[u + 2] += a * wv.z; acc[u + 3] += a * wv.w;
            }
        }
        __syncthreads();
    }
    if (Cout) {
        float* cp = Cout + (size_t)(mt * 32 + ty) * HH + tx * 16;
        #pragma unroll
        for (int u = 0; u < 16; u += 4) {
            float4 f;
            f.x = acc[u]; f.y = acc[u + 1]; f.z = acc[u + 2]; f.w = acc[u + 3];
            *(float4*)(cp + u) = f;
        }
    }
    if (Zthi) {
        __syncthreads();
        float* Tl = &Wl[0][0];  // reuse as [32][132]
        #pragma unroll
        for (int u = 0; u < 16; ++u) Tl[ty * 132 + tx * 16 + u] = acc[u];
        __syncthreads();
        int col = t >> 1, half = t & 1;
        unsigned short hu[16] __attribute__((aligned(16)));
        unsigned short lu[16] __attribute__((aligned(16)));
        #pragma unroll
        for (int rr = 0; rr < 16; ++rr) {
            float v = Tl[(half * 16 + rr) * 132 + col];
            unsigned short hb = f2bf(v);
            hu[rr] = hb;
            lu[rr] = f2bf(v - bf2f(hb));
        }
        size_t ob = (size_t)col * NN + mt * 32 + half * 16;
        *(uint4*)(Zthi + ob)     = *(const uint4*)&hu[0];
        *(uint4*)(Zthi + ob + 8) = *(const uint4*)&hu[8];
        *(uint4*)(Ztlo + ob)     = *(const uint4*)&lu[0];
        *(uint4*)(Ztlo + ob + 8) = *(const uint4*)&lu[8];
    }
}

// K5: S += adj @ Z via per-edge scatter (fp32 atomics)
__global__ void k_spmm(const int* __restrict__ ei, const float* __restrict__ Z,
                       float* __restrict__ S) {
    int idx = blockIdx.x * 256 + threadIdx.x;  // E*32
    int e = idx >> 5, q = idx & 31;
    int r = ei[e], c = ei[EE + e];
    float4 v = *(const float4*)(Z + (size_t)c * HH + q * 4);
    float* sp = S + (size_t)r * HH + q * 4;
    atomicAdd(sp + 0, v.x);
    atomicAdd(sp + 1, v.y);
    atomicAdd(sp + 2, v.z);
    atomicAdd(sp + 3, v.w);
}

// K6: S += pert_adj @ Z, dense MFMA. A = pert_adj (0/1, exact in bf16),
// B = Z as bf16 hi+lo split (fp32-grade accuracy), Zt transposed so all
// fragment reads are contiguous b128. Split-K=8, fp32 atomic epilogue.
__global__ void __launch_bounds__(256) k_mfma_spmm(const float* __restrict__ Padj,
                                                   const unsigned short* __restrict__ Zthi,
                                                   const unsigned short* __restrict__ Ztlo,
                                                   float* __restrict__ S) {
    __shared__ unsigned short Al[64 * 32];
    __shared__ unsigned short Bh[128 * 32];
    __shared__ unsigned short Bl[128 * 32];
    int mt = blockIdx.x >> 3, sk = blockIdx.x & 7;
    int t = threadIdx.x, w = t >> 6, lane = t & 63;
    f32x4 acc[8];
    #pragma unroll
    for (int i = 0; i < 8; ++i) acc[i] = (f32x4){0.f, 0.f, 0.f, 0.f};
    int arow = t >> 2, aq = t & 3;
    int bn = t >> 1, bhalf = t & 1;
    const float* ab = Padj + (size_t)(mt * 64 + arow) * NN + aq * 8;
    const unsigned short* zh = Zthi + (size_t)bn * NN + bhalf * 16;
    const unsigned short* zl = Ztlo + (size_t)bn * NN + bhalf * 16;
    int am = (w * 16 + (lane & 15)) * 32 + (lane >> 4) * 8;
    int bmb = (lane & 15) * 32 + (lane >> 4) * 8;
    for (int ks = 0; ks < 32; ++ks) {
        int k = sk * 1024 + ks * 32;
        float4 f0 = *(const float4*)(ab + k);
        float4 f1 = *(const float4*)(ab + k + 4);
        unsigned u0 = (f0.x != 0.f) ? 0x3F80u : 0u;
        unsigned u1 = (f0.y != 0.f) ? 0x3F80u : 0u;
        unsigned u2 = (f0.z != 0.f) ? 0x3F80u : 0u;
        unsigned u3 = (f0.w != 0.f) ? 0x3F80u : 0u;
        unsigned u4 = (f1.x != 0.f) ? 0x3F80u : 0u;
        unsigned u5 = (f1.y != 0.f) ? 0x3F80u : 0u;
        unsigned u6 = (f1.z != 0.f) ? 0x3F80u : 0u;
        unsigned u7 = (f1.w != 0.f) ? 0x3F80u : 0u;
        uint4 av;
        av.x = u0 | (u1 << 16); av.y = u2 | (u3 << 16);
        av.z = u4 | (u5 << 16); av.w = u6 | (u7 << 16);
        *(uint4*)(Al + arow * 32 + aq * 8) = av;
        *(uint4*)(Bh + bn * 32 + bhalf * 16)     = *(const uint4*)(zh + k);
        *(uint4*)(Bh + bn * 32 + bhalf * 16 + 8) = *(const uint4*)(zh + k + 8);
        *(uint4*)(Bl + bn * 32 + bhalf * 16)     = *(const uint4*)(zl + k);
        *(uint4*)(Bl + bn * 32 + bhalf * 16 + 8) = *(const uint4*)(zl + k + 8);
        __syncthreads();
        short8 a = *(const short8*)(Al + am);
        #pragma unroll
        for (int nt = 0; nt < 8; ++nt) {
            short8 b0 = *(const short8*)(Bh + nt * 16 * 32 + bmb);
            acc[nt] = __builtin_amdgcn_mfma_f32_16x16x32_bf16(a, b0, acc[nt], 0, 0, 0);
            short8 b1 = *(const short8*)(Bl + nt * 16 * 32 + bmb);
            acc[nt] = __builtin_amdgcn_mfma_f32_16x16x32_bf16(a, b1, acc[nt], 0, 0, 0);
        }
        __syncthreads();
    }
    int dc = lane & 15, dr = (lane >> 4) * 4;
    #pragma unroll
    for (int nt = 0; nt < 8; ++nt) {
        #pragma unroll
        for (int rg2 = 0; rg2 < 4; ++rg2)
            atomicAdd(&S[(size_t)(mt * 64 + w * 16 + dr + rg2) * HH + nt * 16 + dc],
                      acc[nt][rg2]);
    }
}

// K7: per-graph mean/max pool of relu(S) -> MLP -> sigmoid
__global__ void __launch_bounds__(256) k_pool(const float* __restrict__ S,
                                              const float* __restrict__ mlpW,
                                              const float* __restrict__ mlpb,
                                              float* __restrict__ outp) {
    __shared__ float ps[256], pm[256], pl[256], r0[256], r1[256];
    int g = blockIdx.x, t = threadIdx.x;
    int col = t & 127, half = t >> 7;
    const float* base = S + (size_t)(g * CC + half * 128) * HH + col;
    float sum = 0.f, mx = -3.0e38f;
    for (int rr = 0; rr < 128; ++rr) {
        float v = fmaxf(base[(size_t)rr * HH], 0.f);
        sum += v;
        mx = fmaxf(mx, v);
    }
    ps[t] = sum; pm[t] = mx;
    __syncthreads();
    if (half == 0) {
        pl[col] = (ps[col] + ps[col + 128]) * (1.0f / 256.0f);
        pl[col + 128] = fmaxf(pm[col], pm[col + 128]);
    }
    __syncthreads();
    r0[t] = pl[t] * mlpW[t * 2 + 0];
    r1[t] = pl[t] * mlpW[t * 2 + 1];
    __syncthreads();
    for (int sft = 128; sft > 0; sft >>= 1) {
        if (t < sft) { r0[t] += r0[t + sft]; r1[t] += r1[t + sft]; }
        __syncthreads();
    }
    if (t == 0) {
        float l0 = r0[0] + mlpb[0];
        float l1 = r1[0] + mlpb[1];
        outp[g * 2 + 0] = 1.0f / (1.0f + expf(-l0));
        outp[g * 2 + 1] = 1.0f / (1.0f + expf(-l1));
    }
}

extern "C" void kernel_launch(void* const* d_in, const int* in_sizes, int n_in,
                              void* d_out, int out_size, void* d_ws, size_t ws_size,
                              hipStream_t stream) {
    (void)in_sizes; (void)n_in; (void)out_size; (void)ws_size;
    const float* x     = (const float*)d_in[0];
    const int*   ei    = (const int*)d_in[1];
    const int*   gid   = (const int*)d_in[2];
    const float* pertW = (const float*)d_in[4];
    const float* pertB = (const float*)d_in[5];
    const float* maskW = (const float*)d_in[6];
    const float* w0    = (const float*)d_in[7];
    const float* w1    = (const float*)d_in[8];
    const float* w2    = (const float*)d_in[9];
    const float* mlpW  = (const float*)d_in[10];
    const float* mlpb  = (const float*)d_in[11];

    float* out  = (float*)d_out;
    float* adj  = out;
    float* padj = out + (size_t)NN * NN;
    float* Mo   = out + 2 * (size_t)NN * NN;
    float* pred = Mo + (size_t)NN * CC;
    float* augp = pred + (size_t)BBg * 2;
    float* xm   = augp + (size_t)BBg * 2;

    char* ws = (char*)d_ws;
    int*            colcnt = (int*)ws;                          // 1 MB
    unsigned char*  coljs  = (unsigned char*)(ws + (1 << 20));  // 4 MB
    float*          Z      = (float*)(ws + (5 << 20));          // 4 MB
    float*          S      = (float*)(ws + (9 << 20));          // 4 MB
    unsigned short* Zthi   = (unsigned short*)(ws + (13 << 20)); // 2 MB
    unsigned short* Ztlo   = (unsigned short*)(ws + (15 << 20)); // 2 MB

    hipMemsetAsync(adj, 0, (size_t)NN * NN * 4, stream);
    hipMemsetAsync(colcnt, 0, (size_t)BBg * NN * 4, stream);
    k_scatter_build<<<EE / 256, 256, 0, stream>>>(ei, adj, colcnt, coljs);
    k_mask<<<(NN * CC / 4) / 256, 256, 0, stream>>>(maskW, gid, x, Mo, xm);
    k_pertadj<<<256, 256, 0, stream>>>(pertW, pertB, gid, colcnt, coljs, padj);

    // pred path: fp32 throughout
    k_gemm<<<256, 256, 0, stream>>>(x, w0, Z, nullptr, nullptr, 256, 0);
    hipMemsetAsync(S, 0, (size_t)NN * HH * 4, stream);
    k_spmm<<<EE * 32 / 256, 256, 0, stream>>>(ei, Z, S);
    k_gemm<<<256, 256, 0, stream>>>(S, w1, Z, nullptr, nullptr, 128, 1);
    hipMemsetAsync(S, 0, (size_t)NN * HH * 4, stream);
    k_spmm<<<EE * 32 / 256, 256, 0, stream>>>(ei, Z, S);
    k_gemm<<<256, 256, 0, stream>>>(S, w2, Z, nullptr, nullptr, 128, 1);
    hipMemsetAsync(S, 0, (size_t)NN * HH * 4, stream);
    k_spmm<<<EE * 32 / 256, 256, 0, stream>>>(ei, Z, S);
    k_pool<<<BBg, 256, 0, stream>>>(S, mlpW, mlpb, pred);

    // aug path: dense MFMA (binary A exact, split-bf16 B)
    k_gemm<<<256, 256, 0, stream>>>(xm, w0, nullptr, Zthi, Ztlo, 256, 0);
    hipMemsetAsync(S, 0, (size_t)NN * HH * 4, stream);
    k_mfma_spmm<<<1024, 256, 0, stream>>>(padj, Zthi, Ztlo, S);
    k_gemm<<<256, 256, 0, stream>>>(S, w1, nullptr, Zthi, Ztlo, 128, 1);
    hipMemsetAsync(S, 0, (size_t)NN * HH * 4, stream);
    k_mfma_spmm<<<1024, 256, 0, stream>>>(padj, Zthi, Ztlo, S);
    k_gemm<<<256, 256, 0, stream>>>(S, w2, nullptr, Zthi, Ztlo, 128, 1);
    hipMemsetAsync(S, 0, (size_t)NN * HH * 4, stream);
    k_mfma_spmm<<<1024, 256, 0, stream>>>(padj, Zthi, Ztlo, S);
    k_pool<<<BBg, 256, 0, stream>>>(S, mlpW, mlpb, augp);
}

// Round 2
// 1243.693 us; speedup vs baseline: 1.5711x; 1.5711x over previous
//
#include <hip/hip_runtime.h>
#include <hip/hip_bf16.h>

#define NN 8192     // total nodes
#define CC 256      // nodes per graph == in_channels
#define BBg 32      // graphs
#define HH 128      // hidden
#define EE 131072   // edges

typedef __attribute__((ext_vector_type(8))) short short8;
typedef __attribute__((ext_vector_type(4))) float f32x4;

// Replicate fp32 hard_where(sigmoid(v)) boundary exactly (see round-0 notes).
__device__ __forceinline__ float hard01(float v) {
    if (v >= 1e-6f) return 1.0f;
    if (v <= 0.0f) return 0.0f;
    float ef = (float)exp(-(double)v);
    float s = 1.0f / (1.0f + ef);
    return (s > 0.5f) ? 1.0f : 0.0f;
}

__device__ __forceinline__ unsigned short f2bf(float f) {
    unsigned u = __float_as_uint(f);
    u += 0x7FFFu + ((u >> 16) & 1u);   // RNE
    return (unsigned short)(u >> 16);
}
__device__ __forceinline__ float bf2f(unsigned short b) {
    return __uint_as_float(((unsigned)b) << 16);
}

// ---- CSR build ----------------------------------------------------------
// K1a: histogram rows + per-(block,col) source-j lists for pert_adj
__global__ void k_hist(const int* __restrict__ ei, int* __restrict__ rowcnt,
                       int* __restrict__ colcnt, unsigned char* __restrict__ coljs) {
    int e = blockIdx.x * 256 + threadIdx.x;
    if (e >= EE) return;
    int r = ei[e], c = ei[EE + e];
    atomicAdd(&rowcnt[r], 1);
    int idx = (r >> 8) * NN + c;
    int slot = atomicAdd(&colcnt[idx], 1);
    if (slot < 16) coljs[(size_t)idx * 16 + slot] = (unsigned char)(r & 255);
}

// K1b: exclusive scan of rowcnt[8192] -> rowptr[8193], rowfill copy
__global__ void k_scan(const int* __restrict__ rowcnt, int* __restrict__ rowptr,
                       int* __restrict__ rowfill) {
    __shared__ int sums[256];
    int t = threadIdx.x;
    int base = t * 32;
    int loc[32];
    int s = 0;
    #pragma unroll
    for (int i = 0; i < 32; ++i) { loc[i] = s; s += rowcnt[base + i]; }
    sums[t] = s;
    __syncthreads();
    if (t == 0) {
        int a = 0;
        for (int i = 0; i < 256; ++i) { int v = sums[i]; sums[i] = a; a += v; }
        rowptr[NN] = a;
    }
    __syncthreads();
    int off = sums[t];
    #pragma unroll
    for (int i = 0; i < 32; ++i) {
        rowptr[base + i] = off + loc[i];
        rowfill[base + i] = off + loc[i];
    }
}

// K1c: fill CSR column indices
__global__ void k_fill(const int* __restrict__ ei, int* __restrict__ rowfill,
                       int* __restrict__ csrcol) {
    int e = blockIdx.x * 256 + threadIdx.x;
    if (e >= EE) return;
    int r = ei[e], c = ei[EE + e];
    int pos = atomicAdd(&rowfill[r], 1);
    csrcol[pos] = c;
}

// K2: stream-write adj from CSR (LDS row accumulator; no global memset/atomics)
__global__ void __launch_bounds__(256) k_adj_write(const int* __restrict__ rowptr,
                                                   const int* __restrict__ csrcol,
                                                   float* __restrict__ adj) {
    __shared__ int cnt[NN];
    int row = blockIdx.x, t = threadIdx.x;
    int4 z = make_int4(0, 0, 0, 0);
    #pragma unroll
    for (int i = 0; i < 8; ++i) *(int4*)&cnt[(i * 256 + t) * 4] = z;
    __syncthreads();
    int start = rowptr[row], end = rowptr[row + 1];
    for (int e = start + t; e < end; e += 256) atomicAdd(&cnt[csrcol[e]], 1);
    __syncthreads();
    float* dst = adj + (size_t)row * NN;
    #pragma unroll
    for (int i = 0; i < 8; ++i) {
        int p = i * 1024 + t * 4;
        float4 f;
        f.x = (float)cnt[p + 0]; f.y = (float)cnt[p + 1];
        f.z = (float)cnt[p + 2]; f.w = (float)cnt[p + 3];
        *(float4*)(dst + p) = f;
    }
}

// K3: M = hard01(mask_W[graph_id] rows), x_masked = M*x
__global__ void k_mask(const float* __restrict__ maskW, const int* __restrict__ gid,
                       const float* __restrict__ x, float* __restrict__ Mo,
                       float* __restrict__ xm) {
    int i = blockIdx.x * 256 + threadIdx.x;
    int base = i * 4;
    int r = base >> 8;
    int c = base & 255;
    int g = gid[r >> 8];
    float4 mv = *(const float4*)(maskW + ((size_t)g << 16) + ((size_t)(r & 255) << 8) + c);
    float4 xv = *(const float4*)(x + ((size_t)r << 8) + c);
    float4 m, o;
    m.x = hard01(mv.x); m.y = hard01(mv.y); m.z = hard01(mv.z); m.w = hard01(mv.w);
    o.x = m.x * xv.x; o.y = m.y * xv.y; o.z = m.z * xv.z; o.w = m.w * xv.w;
    *(float4*)(Mo + ((size_t)r << 8) + c) = m;
    *(float4*)(xm + ((size_t)r << 8) + c) = o;
}

// K4: pert_adj via sparse column lists. Emits fp32 (d_out) AND bf16 copy (ws).
// grid 1024 = b(32) x rt(8 row-tiles of 32) x nc(4 col-chunks of 2048)
__global__ void __launch_bounds__(256) k_pertadj(const float* __restrict__ pertW,
                                                 const float* __restrict__ pertB,
                                                 const int* __restrict__ gid,
                                                 const int* __restrict__ colcnt,
                                                 const unsigned char* __restrict__ coljs,
                                                 float* __restrict__ padj,
                                                 unsigned short* __restrict__ padjb) {
    __shared__ float Pl[32][257];
    int nc = blockIdx.x & 3, rt = (blockIdx.x >> 2) & 7, b = blockIdx.x >> 5;
    int t = threadIdx.x;
    int g = gid[b];
    const float* src = pertW + ((size_t)g << 16) + (size_t)rt * 32 * CC;
    #pragma unroll 4
    for (int i = 0; i < 32; ++i) Pl[i][t] = src[i * CC + t];
    __syncthreads();
    int ty = t >> 6, tx = t & 63;          // ty: 8-row group; tx: col quad
    int ro = ty * 8;
    const float* bsrc = pertB + ((size_t)g << 16) + (size_t)(rt * 32 + ro) * CC;
    for (int it = 0; it < 8; ++it) {
        int n = nc * 2048 + it * 256 + tx * 4;
        int cidx = b * NN + n;
        int4 cnt4 = *(const int4*)(colcnt + cidx);
        const uint4* jp = (const uint4*)(coljs + (size_t)cidx * 16);
        float s[8][4];
        #pragma unroll
        for (int ii = 0; ii < 8; ++ii)
            #pragma unroll
            for (int cc = 0; cc < 4; ++cc) s[ii][cc] = 0.0f;
        #pragma unroll
        for (int cc = 0; cc < 4; ++cc) {
            int cnt = (&cnt4.x)[cc];
            cnt = cnt > 16 ? 16 : cnt;
            if (cnt == 0) continue;
            uint4 jv = jp[cc];
            for (int q = 0; q < cnt; ++q) {
                unsigned word = (q < 8) ? ((q < 4) ? jv.x : jv.y)
                                        : ((q < 12) ? jv.z : jv.w);
                int j = (word >> ((q & 3) * 8)) & 255;
                #pragma unroll
                for (int ii = 0; ii < 8; ++ii) s[ii][cc] += Pl[ro + ii][j];
            }
        }
        bool diag = ((n >> 8) == b);
        #pragma unroll
        for (int ii = 0; ii < 8; ++ii) {
            float4 v = make_float4(s[ii][0], s[ii][1], s[ii][2], s[ii][3]);
            if (diag) {
                float4 bv = *(const float4*)(bsrc + (size_t)ii * CC + (n & 255));
                v.x += bv.x; v.y += bv.y; v.z += bv.z; v.w += bv.w;
            }
            float4 f;
            f.x = hard01(v.x); f.y = hard01(v.y); f.z = hard01(v.z); f.w = hard01(v.w);
            size_t ob = (size_t)(b * CC + rt * 32 + ro + ii) * NN + n;
            *(float4*)(padj + ob) = f;
            ushort4 h;
            h.x = (f.x != 0.f) ? 0x3F80 : 0; h.y = (f.y != 0.f) ? 0x3F80 : 0;
            h.z = (f.z != 0.f) ? 0x3F80 : 0; h.w = (f.w != 0.f) ? 0x3F80 : 0;
            *(ushort4*)(padjb + ob) = h;
        }
    }
}

// K5: out = relu?(sum_p A_p) @ W.  Writes fp32 Cout (pred) or transposed
// bf16 hi/lo split Zt (aug).  A tiles 32 rows, W full [K..][128].
__global__ void __launch_bounds__(256) k_gemm(const float* __restrict__ A,
                                              const float* __restrict__ W,
                                              float* __restrict__ Cout,
                                              unsigned short* __restrict__ Zthi,
                                              unsigned short* __restrict__ Ztlo,
                                              int K, int relu, int parts, int pstride) {
    __shared__ float Al[32][68];
    __shared__ float Wl[64][132];
    int mt = blockIdx.x;
    int t = threadIdx.x;
    int ty = t >> 3, tx = t & 7;
    float acc[16];
    #pragma unroll
    for (int u = 0; u < 16; ++u) acc[u] = 0.0f;
    for (int kc = 0; kc < K; kc += 64) {
        {
            int row = t >> 3, q = t & 7;
            const float* ap = A + (size_t)(mt * 32 + row) * K + kc + q * 8;
            float4 f0 = *(const float4*)ap;
            float4 f1 = *(const float4*)(ap + 4);
            for (int p = 1; p < parts; ++p) {
                float4 g0 = *(const float4*)(ap + (size_t)p * pstride);
                float4 g1 = *(const float4*)(ap + (size_t)p * pstride + 4);
                f0.x += g0.x; f0.y += g0.y; f0.z += g0.z; f0.w += g0.w;
                f1.x += g1.x; f1.y += g1.y; f1.z += g1.z; f1.w += g1.w;
            }
            if (relu) {
                f0.x = fmaxf(f0.x, 0.f); f0.y = fmaxf(f0.y, 0.f);
                f0.z = fmaxf(f0.z, 0.f); f0.w = fmaxf(f0.w, 0.f);
                f1.x = fmaxf(f1.x, 0.f); f1.y = fmaxf(f1.y, 0.f);
                f1.z = fmaxf(f1.z, 0.f); f1.w = fmaxf(f1.w, 0.f);
            }
            Al[row][q * 8 + 0] = f0.x; Al[row][q * 8 + 1] = f0.y;
            Al[row][q * 8 + 2] = f0.z; Al[row][q * 8 + 3] = f0.w;
            Al[row][q * 8 + 4] = f1.x; Al[row][q * 8 + 5] = f1.y;
            Al[row][q * 8 + 6] = f1.z; Al[row][q * 8 + 7] = f1.w;
        }
        {
            int row = t >> 2, q = t & 3;
            const float* wp = W + (size_t)(kc + row) * HH + q * 32;
            #pragma unroll
            for (int u = 0; u < 32; u += 4) {
                float4 f = *(const float4*)(wp + u);
                Wl[row][q * 32 + u + 0] = f.x; Wl[row][q * 32 + u + 1] = f.y;
                Wl[row][q * 32 + u + 2] = f.z; Wl[row][q * 32 + u + 3] = f.w;
            }
        }
        __syncthreads();
        #pragma unroll 4
        for (int kk = 0; kk < 64; ++kk) {
            float a = Al[ty][kk];
            #pragma unroll
            for (int u = 0; u < 16; u += 4) {
                float4 wv = *(const float4*)(&Wl[kk][tx * 16 + u]);
                acc[u + 0] += a * wv.x; acc[u + 1] += a * wv.y;
                acc[u + 2] += a * wv.z; acc[u + 3] += a * wv.w;
            }
        }
        __syncthreads();
    }
    if (Cout) {
        float* cp = Cout + (size_t)(mt * 32 + ty) * HH + tx * 16;
        #pragma unroll
        for (int u = 0; u < 16; u += 4) {
            float4 f;
            f.x = acc[u]; f.y = acc[u + 1]; f.z = acc[u + 2]; f.w = acc[u + 3];
            *(float4*)(cp + u) = f;
        }
    }
    if (Zthi) {
        __syncthreads();
        float* Tl = &Wl[0][0];  // reuse as [32][132]
        #pragma unroll
        for (int u = 0; u < 16; ++u) Tl[ty * 132 + tx * 16 + u] = acc[u];
        __syncthreads();
        int col = t >> 1, half = t & 1;
        unsigned short hu[16] __attribute__((aligned(16)));
        unsigned short lu[16] __attribute__((aligned(16)));
        #pragma unroll
        for (int rr = 0; rr < 16; ++rr) {
            float v = Tl[(half * 16 + rr) * 132 + col];
            unsigned short hb = f2bf(v);
            hu[rr] = hb;
            lu[rr] = f2bf(v - bf2f(hb));
        }
        size_t ob = (size_t)col * NN + mt * 32 + half * 16;
        *(uint4*)(Zthi + ob)     = *(const uint4*)&hu[0];
        *(uint4*)(Zthi + ob + 8) = *(const uint4*)&hu[8];
        *(uint4*)(Ztlo + ob)     = *(const uint4*)&lu[0];
        *(uint4*)(Ztlo + ob + 8) = *(const uint4*)&lu[8];
    }
}

// K6: S = adj @ Z by CSR gather (no atomics, writes every row)
__global__ void k_spmm_gather(const int* __restrict__ rowptr,
                              const int* __restrict__ csrcol,
                              const float* __restrict__ Z,
                              float* __restrict__ S) {
    int t = threadIdx.x;
    int row = blockIdx.x * 2 + (t >> 7);
    int col = t & 127;
    int start = rowptr[row], end = rowptr[row + 1];
    float s = 0.f;
    if (start < end) {
        int c = csrcol[start];
        for (int e = start; e < end; ++e) {
            int cn = (e + 1 < end) ? csrcol[e + 1] : 0;
            s += Z[(size_t)c * HH + col];
            c = cn;
        }
    }
    S[(size_t)row * HH + col] = s;
}

// K7: Sp[sk] = padjb(k-slice sk) @ Z  (bf16 A direct, hi/lo split B,
// split-K=4 partials, plain stores).  grid 512 = mt(128) x sk(4)
__global__ void __launch_bounds__(256) k_mfma_spmm(const unsigned short* __restrict__ padjb,
                                                   const unsigned short* __restrict__ Zthi,
                                                   const unsigned short* __restrict__ Ztlo,
                                                   float* __restrict__ Sp) {
    __shared__ unsigned short Al[64 * 72];
    __shared__ unsigned short Bh[128 * 72];
    __shared__ unsigned short Bl[128 * 72];
    int mt = blockIdx.x >> 2, sk = blockIdx.x & 3;
    int t = threadIdx.x, w = t >> 6, lane = t & 63;
    f32x4 acc[8];
    #pragma unroll
    for (int i = 0; i < 8; ++i) acc[i] = (f32x4){0.f, 0.f, 0.f, 0.f};
    int arow = t >> 2, aq = t & 3;
    int bn = t >> 1, bq = t & 1;
    const unsigned short* ab = padjb + (size_t)(mt * 64 + arow) * NN + aq * 16;
    const unsigned short* zh = Zthi + (size_t)bn * NN + bq * 32;
    const unsigned short* zl = Ztlo + (size_t)bn * NN + bq * 32;
    int am = (w * 16 + (lane & 15)) * 72 + (lane >> 4) * 8;
    int bmb = (lane & 15) * 72 + (lane >> 4) * 8;
    for (int st = 0; st < 32; ++st) {
        int k = sk * 2048 + st * 64;
        *(uint4*)(Al + arow * 72 + aq * 16)     = *(const uint4*)(ab + k);
        *(uint4*)(Al + arow * 72 + aq * 16 + 8) = *(const uint4*)(ab + k + 8);
        #pragma unroll
        for (int u = 0; u < 32; u += 8) {
            *(uint4*)(Bh + bn * 72 + bq * 32 + u) = *(const uint4*)(zh + k + u);
            *(uint4*)(Bl + bn * 72 + bq * 32 + u) = *(const uint4*)(zl + k + u);
        }
        __syncthreads();
        #pragma unroll
        for (int ksub = 0; ksub < 2; ++ksub) {
            short8 a = *(const short8*)(Al + am + ksub * 32);
            #pragma unroll
            for (int nt = 0; nt < 8; ++nt) {
                short8 b0 = *(const short8*)(Bh + nt * 16 * 72 + bmb + ksub * 32);
                acc[nt] = __builtin_amdgcn_mfma_f32_16x16x32_bf16(a, b0, acc[nt], 0, 0, 0);
                short8 b1 = *(const short8*)(Bl + nt * 16 * 72 + bmb + ksub * 32);
                acc[nt] = __builtin_amdgcn_mfma_f32_16x16x32_bf16(a, b1, acc[nt], 0, 0, 0);
            }
        }
        __syncthreads();
    }
    int dc = lane & 15, dr = (lane >> 4) * 4;
    float* base = Sp + (size_t)sk * NN * HH + (size_t)(mt * 64 + w * 16 + dr) * HH;
    #pragma unroll
    for (int nt = 0; nt < 8; ++nt)
        #pragma unroll
        for (int rg2 = 0; rg2 < 4; ++rg2)
            base[(size_t)rg2 * HH + nt * 16 + dc] = acc[nt][rg2];
}

// K8: per-graph mean/max pool of relu(sum_p Sp) -> MLP -> sigmoid
__global__ void __launch_bounds__(256) k_pool(const float* __restrict__ S,
                                              const float* __restrict__ mlpW,
                                              const float* __restrict__ mlpb,
                                              float* __restrict__ outp,
                                              int parts, int pstride) {
    __shared__ float ps[256], pm[256], pl[256], r0[256], r1[256];
    int g = blockIdx.x, t = threadIdx.x;
    int col = t & 127, half = t >> 7;
    const float* base = S + (size_t)(g * CC + half * 128) * HH + col;
    float sum = 0.f, mx = -3.0e38f;
    for (int rr = 0; rr < 128; ++rr) {
        float v = base[(size_t)rr * HH];
        for (int p = 1; p < parts; ++p) v += base[(size_t)p * pstride + (size_t)rr * HH];
        v = fmaxf(v, 0.f);
        sum += v;
        mx = fmaxf(mx, v);
    }
    ps[t] = sum; pm[t] = mx;
    __syncthreads();
    if (half == 0) {
        pl[col] = (ps[col] + ps[col + 128]) * (1.0f / 256.0f);
        pl[col + 128] = fmaxf(pm[col], pm[col + 128]);
    }
    __syncthreads();
    r0[t] = pl[t] * mlpW[t * 2 + 0];
    r1[t] = pl[t] * mlpW[t * 2 + 1];
    __syncthreads();
    for (int sft = 128; sft > 0; sft >>= 1) {
        if (t < sft) { r0[t] += r0[t + sft]; r1[t] += r1[t + sft]; }
        __syncthreads();
    }
    if (t == 0) {
        float l0 = r0[0] + mlpb[0];
        float l1 = r1[0] + mlpb[1];
        outp[g * 2 + 0] = 1.0f / (1.0f + expf(-l0));
        outp[g * 2 + 1] = 1.0f / (1.0f + expf(-l1));
    }
}

extern "C" void kernel_launch(void* const* d_in, const int* in_sizes, int n_in,
                              void* d_out, int out_size, void* d_ws, size_t ws_size,
                              hipStream_t stream) {
    (void)in_sizes; (void)n_in; (void)out_size; (void)ws_size;
    const float* x     = (const float*)d_in[0];
    const int*   ei    = (const int*)d_in[1];
    const int*   gid   = (const int*)d_in[2];
    const float* pertW = (const float*)d_in[4];
    const float* pertB = (const float*)d_in[5];
    const float* maskW = (const float*)d_in[6];
    const float* w0    = (const float*)d_in[7];
    const float* w1    = (const float*)d_in[8];
    const float* w2    = (const float*)d_in[9];
    const float* mlpW  = (const float*)d_in[10];
    const float* mlpb  = (const float*)d_in[11];

    float* out  = (float*)d_out;
    float* adj  = out;
    float* padj = out + (size_t)NN * NN;
    float* Mo   = out + 2 * (size_t)NN * NN;
    float* pred = Mo + (size_t)NN * CC;
    float* augp = pred + (size_t)BBg * 2;
    float* xm   = augp + (size_t)BBg * 2;

    char* ws = (char*)d_ws;
    int*            rowcnt  = (int*)ws;                            // 32KB
    int*            rowptr  = (int*)(ws + (64 << 10));             // 33KB
    int*            rowfill = (int*)(ws + (128 << 10));            // 32KB
    int*            colcnt  = (int*)(ws + (1 << 20));              // 1MB
    unsigned char*  coljs   = (unsigned char*)(ws + (2 << 20));    // 4MB
    int*            csrcol  = (int*)(ws + (6 << 20));              // 512KB
    float*          Z       = (float*)(ws + (7 << 20));            // 4MB
    float*          S       = (float*)(ws + (11 << 20));           // 4MB
    unsigned short* Zthi    = (unsigned short*)(ws + (15 << 20));  // 2MB
    unsigned short* Ztlo    = (unsigned short*)(ws + (17 << 20));  // 2MB
    float*          Sp      = (float*)(ws + (19 << 20));           // 16MB
    unsigned short* padjb   = (unsigned short*)(ws + (35 << 20));  // 134MB
    const int PS = NN * HH;  // partial stride (elements)

    hipMemsetAsync(rowcnt, 0, NN * 4, stream);
    hipMemsetAsync(colcnt, 0, (size_t)BBg * NN * 4, stream);
    k_hist<<<EE / 256, 256, 0, stream>>>(ei, rowcnt, colcnt, coljs);
    k_scan<<<1, 256, 0, stream>>>(rowcnt, rowptr, rowfill);
    k_fill<<<EE / 256, 256, 0, stream>>>(ei, rowfill, csrcol);
    k_adj_write<<<NN, 256, 0, stream>>>(rowptr, csrcol, adj);
    k_mask<<<(NN * CC / 4) / 256, 256, 0, stream>>>(maskW, gid, x, Mo, xm);
    k_pertadj<<<1024, 256, 0, stream>>>(pertW, pertB, gid, colcnt, coljs, padj, padjb);

    // pred path: fp32, gather SpMM (no atomics)
    k_gemm<<<256, 256, 0, stream>>>(x, w0, Z, nullptr, nullptr, 256, 0, 1, 0);
    k_spmm_gather<<<NN / 2, 256, 0, stream>>>(rowptr, csrcol, Z, S);
    k_gemm<<<256, 256, 0, stream>>>(S, w1, Z, nullptr, nullptr, 128, 1, 1, 0);
    k_spmm_gather<<<NN / 2, 256, 0, stream>>>(rowptr, csrcol, Z, S);
    k_gemm<<<256, 256, 0, stream>>>(S, w2, Z, nullptr, nullptr, 128, 1, 1, 0);
    k_spmm_gather<<<NN / 2, 256, 0, stream>>>(rowptr, csrcol, Z, S);
    k_pool<<<BBg, 256, 0, stream>>>(S, mlpW, mlpb, pred, 1, 0);

    // aug path: dense MFMA on bf16 pert_adj, split-K partials
    k_gemm<<<256, 256, 0, stream>>>(xm, w0, nullptr, Zthi, Ztlo, 256, 0, 1, 0);
    k_mfma_spmm<<<512, 256, 0, stream>>>(padjb, Zthi, Ztlo, Sp);
    k_gemm<<<256, 256, 0, stream>>>(Sp, w1, nullptr, Zthi, Ztlo, 128, 1, 4, PS);
    k_mfma_spmm<<<512, 256, 0, stream>>>(padjb, Zthi, Ztlo, Sp);
    k_gemm<<<256, 256, 0, stream>>>(Sp, w2, nullptr, Zthi, Ztlo, 128, 1, 4, PS);
    k_mfma_spmm<<<512, 256, 0, stream>>>(padjb, Zthi, Ztlo, Sp);
    k_pool<<<BBg, 256, 0, stream>>>(Sp, mlpW, mlpb, augp, 4, PS);
}

// Round 3
// 1104.331 us; speedup vs baseline: 1.7694x; 1.1262x over previous
//
#include <hip/hip_runtime.h>
#include <hip/hip_bf16.h>

#define NN 8192     // total nodes
#define CC 256      // nodes per graph == in_channels
#define BBg 32      // graphs
#define HH 128      // hidden
#define EE 131072   // edges

typedef __attribute__((ext_vector_type(8))) short short8;
typedef __attribute__((ext_vector_type(4))) float f32x4;
typedef unsigned long long ull;

// Replicate fp32 hard_where(sigmoid(v)) boundary exactly (see round-0 notes).
__device__ __forceinline__ float hard01(float v) {
    if (v >= 1e-6f) return 1.0f;
    if (v <= 0.0f) return 0.0f;
    float ef = (float)exp(-(double)v);
    float s = 1.0f / (1.0f + ef);
    return (s > 0.5f) ? 1.0f : 0.0f;
}

__device__ __forceinline__ unsigned short f2bf(float f) {
    unsigned u = __float_as_uint(f);
    u += 0x7FFFu + ((u >> 16) & 1u);   // RNE
    return (unsigned short)(u >> 16);
}
__device__ __forceinline__ float bf2f(unsigned short b) {
    return __uint_as_float(((unsigned)b) << 16);
}

// ---- CSR build ----------------------------------------------------------
__global__ void k_hist(const int* __restrict__ ei, int* __restrict__ rowcnt,
                       int* __restrict__ colcnt, unsigned char* __restrict__ coljs) {
    int e = blockIdx.x * 256 + threadIdx.x;
    if (e >= EE) return;
    int r = ei[e], c = ei[EE + e];
    atomicAdd(&rowcnt[r], 1);
    int idx = (r >> 8) * NN + c;
    int slot = atomicAdd(&colcnt[idx], 1);
    if (slot < 16) coljs[(size_t)idx * 16 + slot] = (unsigned char)(r & 255);
}

__global__ void k_scan(const int* __restrict__ rowcnt, int* __restrict__ rowptr,
                       int* __restrict__ rowfill) {
    __shared__ int sums[256];
    int t = threadIdx.x;
    int base = t * 32;
    int loc[32];
    int s = 0;
    #pragma unroll
    for (int i = 0; i < 32; ++i) { loc[i] = s; s += rowcnt[base + i]; }
    sums[t] = s;
    __syncthreads();
    if (t == 0) {
        int a = 0;
        for (int i = 0; i < 256; ++i) { int v = sums[i]; sums[i] = a; a += v; }
        rowptr[NN] = a;
    }
    __syncthreads();
    int off = sums[t];
    #pragma unroll
    for (int i = 0; i < 32; ++i) {
        rowptr[base + i] = off + loc[i];
        rowfill[base + i] = off + loc[i];
    }
}

__global__ void k_fill(const int* __restrict__ ei, int* __restrict__ rowfill,
                       int* __restrict__ csrcol) {
    int e = blockIdx.x * 256 + threadIdx.x;
    if (e >= EE) return;
    int r = ei[e], c = ei[EE + e];
    int pos = atomicAdd(&rowfill[r], 1);
    csrcol[pos] = c;
}

// K2: stream-write adj from CSR (LDS row accumulator)
__global__ void __launch_bounds__(256) k_adj_write(const int* __restrict__ rowptr,
                                                   const int* __restrict__ csrcol,
                                                   float* __restrict__ adj) {
    __shared__ int cnt[NN];
    int row = blockIdx.x, t = threadIdx.x;
    int4 z = make_int4(0, 0, 0, 0);
    #pragma unroll
    for (int i = 0; i < 8; ++i) *(int4*)&cnt[(i * 256 + t) * 4] = z;
    __syncthreads();
    int start = rowptr[row], end = rowptr[row + 1];
    for (int e = start + t; e < end; e += 256) atomicAdd(&cnt[csrcol[e]], 1);
    __syncthreads();
    float* dst = adj + (size_t)row * NN;
    #pragma unroll
    for (int i = 0; i < 8; ++i) {
        int p = i * 1024 + t * 4;
        float4 f;
        f.x = (float)cnt[p + 0]; f.y = (float)cnt[p + 1];
        f.z = (float)cnt[p + 2]; f.w = (float)cnt[p + 3];
        *(float4*)(dst + p) = f;
    }
}

// K3: M = hard01(mask_W[graph_id] rows), x_masked = M*x
__global__ void k_mask(const float* __restrict__ maskW, const int* __restrict__ gid,
                       const float* __restrict__ x, float* __restrict__ Mo,
                       float* __restrict__ xm) {
    int i = blockIdx.x * 256 + threadIdx.x;
    int base = i * 4;
    int r = base >> 8;
    int c = base & 255;
    int g = gid[r >> 8];
    float4 mv = *(const float4*)(maskW + ((size_t)g << 16) + ((size_t)(r & 255) << 8) + c);
    float4 xv = *(const float4*)(x + ((size_t)r << 8) + c);
    float4 m, o;
    m.x = hard01(mv.x); m.y = hard01(mv.y); m.z = hard01(mv.z); m.w = hard01(mv.w);
    o.x = m.x * xv.x; o.y = m.y * xv.y; o.z = m.z * xv.z; o.w = m.w * xv.w;
    *(float4*)(Mo + ((size_t)r << 8) + c) = m;
    *(float4*)(xm + ((size_t)r << 8) + c) = o;
}

// K4: pert_adj -> fp32 padj (d_out) + 1-bit packed padjbits (ws).
// grid 1024 = b(32) x rt(8) x nc(4); thread covers 8 rows x 8 cols per it.
__global__ void __launch_bounds__(256) k_pertadj(const float* __restrict__ pertW,
                                                 const float* __restrict__ pertB,
                                                 const int* __restrict__ gid,
                                                 const int* __restrict__ colcnt,
                                                 const unsigned char* __restrict__ coljs,
                                                 float* __restrict__ padj,
                                                 unsigned char* __restrict__ padjbits) {
    __shared__ float Pl[32][257];
    int nc = blockIdx.x & 3, rt = (blockIdx.x >> 2) & 7, b = blockIdx.x >> 5;
    int t = threadIdx.x;
    int g = gid[b];
    const float* src = pertW + ((size_t)g << 16) + (size_t)rt * 32 * CC;
    #pragma unroll 4
    for (int i = 0; i < 32; ++i) Pl[i][t] = src[i * CC + t];
    __syncthreads();
    int ty = t >> 6, tx = t & 63;          // ty: 8-row group; tx: 8-col group
    int ro = ty * 8;
    const float* bsrc = pertB + ((size_t)g << 16) + (size_t)(rt * 32 + ro) * CC;
    for (int it = 0; it < 4; ++it) {
        unsigned bits[8];
        #pragma unroll
        for (int ii = 0; ii < 8; ++ii) bits[ii] = 0;
        #pragma unroll
        for (int half = 0; half < 2; ++half) {
            int n = nc * 2048 + it * 512 + tx * 8 + half * 4;
            int cidx = b * NN + n;
            int4 cnt4 = *(const int4*)(colcnt + cidx);
            const uint4* jp = (const uint4*)(coljs + (size_t)cidx * 16);
            float s[8][4];
            #pragma unroll
            for (int ii = 0; ii < 8; ++ii)
                #pragma unroll
                for (int cc = 0; cc < 4; ++cc) s[ii][cc] = 0.0f;
            #pragma unroll
            for (int cc = 0; cc < 4; ++cc) {
                int cnt = (&cnt4.x)[cc];
                cnt = cnt > 16 ? 16 : cnt;
                if (cnt == 0) continue;
                uint4 jv = jp[cc];
                for (int q = 0; q < cnt; ++q) {
                    unsigned word = (q < 8) ? ((q < 4) ? jv.x : jv.y)
                                            : ((q < 12) ? jv.z : jv.w);
                    int j = (word >> ((q & 3) * 8)) & 255;
                    #pragma unroll
                    for (int ii = 0; ii < 8; ++ii) s[ii][cc] += Pl[ro + ii][j];
                }
            }
            bool diag = ((n >> 8) == b);
            #pragma unroll
            for (int ii = 0; ii < 8; ++ii) {
                float4 v = make_float4(s[ii][0], s[ii][1], s[ii][2], s[ii][3]);
                if (diag) {
                    float4 bv = *(const float4*)(bsrc + (size_t)ii * CC + (n & 255));
                    v.x += bv.x; v.y += bv.y; v.z += bv.z; v.w += bv.w;
                }
                float4 f;
                f.x = hard01(v.x); f.y = hard01(v.y); f.z = hard01(v.z); f.w = hard01(v.w);
                size_t ob = (size_t)(b * CC + rt * 32 + ro + ii) * NN + n;
                *(float4*)(padj + ob) = f;
                unsigned nib = (f.x != 0.f ? 1u : 0u) | (f.y != 0.f ? 2u : 0u) |
                               (f.z != 0.f ? 4u : 0u) | (f.w != 0.f ? 8u : 0u);
                bits[ii] |= nib << (half * 4);
            }
        }
        #pragma unroll
        for (int ii = 0; ii < 8; ++ii) {
            size_t bb = (size_t)(b * CC + rt * 32 + ro + ii) * (NN / 8)
                        + nc * 256 + it * 64 + tx;
            padjbits[bb] = (unsigned char)bits[ii];
        }
    }
}

// K5: dual GEMM: Zp = relu?(Ap)@W  and  Zt(hi/lo bf16, transposed) = relu?(sum Aa)@W
__global__ void __launch_bounds__(256) k_gemm_dual(const float* __restrict__ Ap,
                                                   const float* __restrict__ Aa,
                                                   const float* __restrict__ W,
                                                   float* __restrict__ Zp,
                                                   unsigned short* __restrict__ Zthi,
                                                   unsigned short* __restrict__ Ztlo,
                                                   int K, int relu, int aparts, int apstride) {
    __shared__ float Alp[32][68];
    __shared__ float Ala[32][68];
    __shared__ float Wl[64][132];
    int mt = blockIdx.x;
    int t = threadIdx.x;
    int ty = t >> 3, tx = t & 7;
    float accp[16], acca[16];
    #pragma unroll
    for (int u = 0; u < 16; ++u) { accp[u] = 0.0f; acca[u] = 0.0f; }
    for (int kc = 0; kc < K; kc += 64) {
        int row = t >> 3, q = t & 7;
        {
            const float* ap = Ap + (size_t)(mt * 32 + row) * K + kc + q * 8;
            float4 f0 = *(const float4*)ap;
            float4 f1 = *(const float4*)(ap + 4);
            if (relu) {
                f0.x = fmaxf(f0.x, 0.f); f0.y = fmaxf(f0.y, 0.f);
                f0.z = fmaxf(f0.z, 0.f); f0.w = fmaxf(f0.w, 0.f);
                f1.x = fmaxf(f1.x, 0.f); f1.y = fmaxf(f1.y, 0.f);
                f1.z = fmaxf(f1.z, 0.f); f1.w = fmaxf(f1.w, 0.f);
            }
            *(float4*)&Alp[row][q * 8] = f0;
            *(float4*)&Alp[row][q * 8 + 4] = f1;
        }
        {
            const float* ap = Aa + (size_t)(mt * 32 + row) * K + kc + q * 8;
            float4 f0 = *(const float4*)ap;
            float4 f1 = *(const float4*)(ap + 4);
            for (int p = 1; p < aparts; ++p) {
                float4 g0 = *(const float4*)(ap + (size_t)p * apstride);
                float4 g1 = *(const float4*)(ap + (size_t)p * apstride + 4);
                f0.x += g0.x; f0.y += g0.y; f0.z += g0.z; f0.w += g0.w;
                f1.x += g1.x; f1.y += g1.y; f1.z += g1.z; f1.w += g1.w;
            }
            if (relu) {
                f0.x = fmaxf(f0.x, 0.f); f0.y = fmaxf(f0.y, 0.f);
                f0.z = fmaxf(f0.z, 0.f); f0.w = fmaxf(f0.w, 0.f);
                f1.x = fmaxf(f1.x, 0.f); f1.y = fmaxf(f1.y, 0.f);
                f1.z = fmaxf(f1.z, 0.f); f1.w = fmaxf(f1.w, 0.f);
            }
            *(float4*)&Ala[row][q * 8] = f0;
            *(float4*)&Ala[row][q * 8 + 4] = f1;
        }
        {
            int wrow = t >> 2, wq = t & 3;
            const float* wp = W + (size_t)(kc + wrow) * HH + wq * 32;
            #pragma unroll
            for (int u = 0; u < 32; u += 4)
                *(float4*)&Wl[wrow][wq * 32 + u] = *(const float4*)(wp + u);
        }
        __syncthreads();
        #pragma unroll 2
        for (int kk = 0; kk < 64; ++kk) {
            float a = Alp[ty][kk];
            float b2 = Ala[ty][kk];
            #pragma unroll
            for (int u = 0; u < 16; u += 4) {
                float4 wv = *(const float4*)(&Wl[kk][tx * 16 + u]);
                accp[u + 0] += a * wv.x; accp[u + 1] += a * wv.y;
                accp[u + 2] += a * wv.z; accp[u + 3] += a * wv.w;
                acca[u + 0] += b2 * wv.x; acca[u + 1] += b2 * wv.y;
                acca[u + 2] += b2 * wv.z; acca[u + 3] += b2 * wv.w;
            }
        }
        __syncthreads();
    }
    {
        float* cp = Zp + (size_t)(mt * 32 + ty) * HH + tx * 16;
        #pragma unroll
        for (int u = 0; u < 16; u += 4) {
            float4 f;
            f.x = accp[u]; f.y = accp[u + 1]; f.z = accp[u + 2]; f.w = accp[u + 3];
            *(float4*)(cp + u) = f;
        }
    }
    {
        __syncthreads();
        float* Tl = &Wl[0][0];  // reuse as [32][132]
        #pragma unroll
        for (int u = 0; u < 16; ++u) Tl[ty * 132 + tx * 16 + u] = acca[u];
        __syncthreads();
        int col = t >> 1, half = t & 1;
        unsigned short hu[16] __attribute__((aligned(16)));
        unsigned short lu[16] __attribute__((aligned(16)));
        #pragma unroll
        for (int rr = 0; rr < 16; ++rr) {
            float v = Tl[(half * 16 + rr) * 132 + col];
            unsigned short hb = f2bf(v);
            hu[rr] = hb;
            lu[rr] = f2bf(v - bf2f(hb));
        }
        size_t ob = (size_t)col * NN + mt * 32 + half * 16;
        *(uint4*)(Zthi + ob)     = *(const uint4*)&hu[0];
        *(uint4*)(Zthi + ob + 8) = *(const uint4*)&hu[8];
        *(uint4*)(Ztlo + ob)     = *(const uint4*)&lu[0];
        *(uint4*)(Ztlo + ob + 8) = *(const uint4*)&lu[8];
    }
}

// K6: S = adj @ Z by CSR gather (no atomics)
__global__ void k_spmm_gather(const int* __restrict__ rowptr,
                              const int* __restrict__ csrcol,
                              const float* __restrict__ Z,
                              float* __restrict__ S) {
    int t = threadIdx.x;
    int row = blockIdx.x * 2 + (t >> 7);
    int col = t & 127;
    int start = rowptr[row], end = rowptr[row + 1];
    float s = 0.f;
    if (start < end) {
        int c = csrcol[start];
        for (int e = start; e < end; ++e) {
            int cn = (e + 1 < end) ? csrcol[e + 1] : 0;
            s += Z[(size_t)c * HH + col];
            c = cn;
        }
    }
    S[(size_t)row * HH + col] = s;
}

// K7: Sp[sk] = pert_adj(bits, k-slice sk) @ Z.  A bits global->regs (L2),
// B hi/lo bf16 in LDS, 2 m-tiles/wave, split-K=8 plain partial stores.
// grid 512 = mt(64: 128-row tiles) x sk(8: K-slices of 1024)
__global__ void __launch_bounds__(256) k_mfma_spmm(const unsigned char* __restrict__ padjbits,
                                                   const unsigned short* __restrict__ Zthi,
                                                   const unsigned short* __restrict__ Ztlo,
                                                   float* __restrict__ Sp) {
    __shared__ unsigned short Bh[128 * 72];
    __shared__ unsigned short Bl[128 * 72];
    int mt = blockIdx.x >> 3, sk = blockIdx.x & 7;
    int t = threadIdx.x, w = t >> 6, lane = t & 63;
    int quad = lane >> 4, l15 = lane & 15;
    f32x4 acc[2][8];
    #pragma unroll
    for (int m = 0; m < 2; ++m)
        #pragma unroll
        for (int i = 0; i < 8; ++i) acc[m][i] = (f32x4){0.f, 0.f, 0.f, 0.f};
    int bn = t >> 1, bq = t & 1;
    const unsigned short* zh = Zthi + (size_t)bn * NN + bq * 32;
    const unsigned short* zl = Ztlo + (size_t)bn * NN + bq * 32;
    int row0 = mt * 128 + w * 32 + l15;
    const ull* ab0 = (const ull*)(padjbits + (size_t)row0 * (NN / 8) + sk * 128);
    const ull* ab1 = (const ull*)(padjbits + (size_t)(row0 + 16) * (NN / 8) + sk * 128);
    int ldsw = bn * 72 + bq * 32;
    int bmb = l15 * 72 + quad * 8;
    for (int st = 0; st < 16; ++st) {
        int k = sk * 1024 + st * 64;
        ull bits0 = ab0[st];
        ull bits1 = ab1[st];
        *(uint4*)(Bh + ldsw + 0)  = *(const uint4*)(zh + k);
        *(uint4*)(Bh + ldsw + 8)  = *(const uint4*)(zh + k + 8);
        *(uint4*)(Bh + ldsw + 16) = *(const uint4*)(zh + k + 16);
        *(uint4*)(Bh + ldsw + 24) = *(const uint4*)(zh + k + 24);
        *(uint4*)(Bl + ldsw + 0)  = *(const uint4*)(zl + k);
        *(uint4*)(Bl + ldsw + 8)  = *(const uint4*)(zl + k + 8);
        *(uint4*)(Bl + ldsw + 16) = *(const uint4*)(zl + k + 16);
        *(uint4*)(Bl + ldsw + 24) = *(const uint4*)(zl + k + 24);
        __syncthreads();
        #pragma unroll
        for (int ksub = 0; ksub < 2; ++ksub) {
            unsigned b0 = ((unsigned)(bits0 >> (ksub * 32)) >> (quad * 8)) & 0xFFu;
            unsigned b1 = ((unsigned)(bits1 >> (ksub * 32)) >> (quad * 8)) & 0xFFu;
            short8 a0, a1;
            #pragma unroll
            for (int j = 0; j < 8; ++j) {
                a0[j] = (b0 & (1u << j)) ? (short)0x3F80 : (short)0;
                a1[j] = (b1 & (1u << j)) ? (short)0x3F80 : (short)0;
            }
            #pragma unroll
            for (int nt = 0; nt < 8; ++nt) {
                short8 fh = *(const short8*)(Bh + nt * 16 * 72 + bmb + ksub * 32);
                short8 fl = *(const short8*)(Bl + nt * 16 * 72 + bmb + ksub * 32);
                acc[0][nt] = __builtin_amdgcn_mfma_f32_16x16x32_bf16(a0, fh, acc[0][nt], 0, 0, 0);
                acc[0][nt] = __builtin_amdgcn_mfma_f32_16x16x32_bf16(a0, fl, acc[0][nt], 0, 0, 0);
                acc[1][nt] = __builtin_amdgcn_mfma_f32_16x16x32_bf16(a1, fh, acc[1][nt], 0, 0, 0);
                acc[1][nt] = __builtin_amdgcn_mfma_f32_16x16x32_bf16(a1, fl, acc[1][nt], 0, 0, 0);
            }
        }
        __syncthreads();
    }
    int dc = l15, dr = quad * 4;
    float* base = Sp + (size_t)sk * NN * HH + (size_t)(mt * 128 + w * 32 + dr) * HH;
    #pragma unroll
    for (int m = 0; m < 2; ++m)
        #pragma unroll
        for (int nt = 0; nt < 8; ++nt)
            #pragma unroll
            for (int r = 0; r < 4; ++r)
                base[(size_t)(m * 16 + r) * HH + nt * 16 + dc] = acc[m][nt][r];
}

// K8: fused pools: block 0..31 pred (parts=1), 32..63 aug (parts=8)
__global__ void __launch_bounds__(256) k_pool2(const float* __restrict__ S,
                                               const float* __restrict__ Sp,
                                               const float* __restrict__ mlpW,
                                               const float* __restrict__ mlpb,
                                               float* __restrict__ pred,
                                               float* __restrict__ augp,
                                               int apstride) {
    __shared__ float ps[256], pm[256], pl[256], r0[256], r1[256];
    int aug = blockIdx.x >> 5, g = blockIdx.x & 31, t = threadIdx.x;
    const float* Sb = aug ? Sp : S;
    int parts = aug ? 8 : 1;
    float* outp = aug ? augp : pred;
    int col = t & 127, half = t >> 7;
    const float* base = Sb + (size_t)(g * CC + half * 128) * HH + col;
    float sum = 0.f, mx = -3.0e38f;
    for (int rr = 0; rr < 128; ++rr) {
        float v = base[(size_t)rr * HH];
        for (int p = 1; p < parts; ++p) v += base[(size_t)p * apstride + (size_t)rr * HH];
        v = fmaxf(v, 0.f);
        sum += v;
        mx = fmaxf(mx, v);
    }
    ps[t] = sum; pm[t] = mx;
    __syncthreads();
    if (half == 0) {
        pl[col] = (ps[col] + ps[col + 128]) * (1.0f / 256.0f);
        pl[col + 128] = fmaxf(pm[col], pm[col + 128]);
    }
    __syncthreads();
    r0[t] = pl[t] * mlpW[t * 2 + 0];
    r1[t] = pl[t] * mlpW[t * 2 + 1];
    __syncthreads();
    for (int sft = 128; sft > 0; sft >>= 1) {
        if (t < sft) { r0[t] += r0[t + sft]; r1[t] += r1[t + sft]; }
        __syncthreads();
    }
    if (t == 0) {
        float l0 = r0[0] + mlpb[0];
        float l1 = r1[0] + mlpb[1];
        outp[g * 2 + 0] = 1.0f / (1.0f + expf(-l0));
        outp[g * 2 + 1] = 1.0f / (1.0f + expf(-l1));
    }
}

extern "C" void kernel_launch(void* const* d_in, const int* in_sizes, int n_in,
                              void* d_out, int out_size, void* d_ws, size_t ws_size,
                              hipStream_t stream) {
    (void)in_sizes; (void)n_in; (void)out_size; (void)ws_size;
    const float* x     = (const float*)d_in[0];
    const int*   ei    = (const int*)d_in[1];
    const int*   gid   = (const int*)d_in[2];
    const float* pertW = (const float*)d_in[4];
    const float* pertB = (const float*)d_in[5];
    const float* maskW = (const float*)d_in[6];
    const float* w0    = (const float*)d_in[7];
    const float* w1    = (const float*)d_in[8];
    const float* w2    = (const float*)d_in[9];
    const float* mlpW  = (const float*)d_in[10];
    const float* mlpb  = (const float*)d_in[11];

    float* out  = (float*)d_out;
    float* adj  = out;
    float* padj = out + (size_t)NN * NN;
    float* Mo   = out + 2 * (size_t)NN * NN;
    float* pred = Mo + (size_t)NN * CC;
    float* augp = pred + (size_t)BBg * 2;
    float* xm   = augp + (size_t)BBg * 2;

    char* ws = (char*)d_ws;
    int*            colcnt   = (int*)ws;                            // 1MB
    int*            rowcnt   = (int*)(ws + (1 << 20));              // 32KB (contig w/ colcnt)
    int*            rowptr   = (int*)(ws + (1 << 20) + (64 << 10)); // 33KB
    int*            rowfill  = (int*)(ws + (1 << 20) + (128 << 10));// 32KB
    unsigned char*  coljs    = (unsigned char*)(ws + (2 << 20));    // 4MB
    int*            csrcol   = (int*)(ws + (6 << 20));              // 512KB
    float*          Z        = (float*)(ws + (7 << 20));            // 4MB
    float*          S        = (float*)(ws + (11 << 20));           // 4MB
    unsigned short* Zthi     = (unsigned short*)(ws + (15 << 20));  // 2MB
    unsigned short* Ztlo     = (unsigned short*)(ws + (17 << 20));  // 2MB
    float*          Sp       = (float*)(ws + (19 << 20));           // 32MB (8 partials)
    unsigned char*  padjbits = (unsigned char*)(ws + (51 << 20));   // 8MB
    const int PS = NN * HH;  // partial stride (elements)

    hipMemsetAsync(colcnt, 0, (1 << 20) + (32 << 10), stream);  // colcnt + rowcnt
    k_hist<<<EE / 256, 256, 0, stream>>>(ei, rowcnt, colcnt, coljs);
    k_scan<<<1, 256, 0, stream>>>(rowcnt, rowptr, rowfill);
    k_fill<<<EE / 256, 256, 0, stream>>>(ei, rowfill, csrcol);
    k_adj_write<<<NN, 256, 0, stream>>>(rowptr, csrcol, adj);
    k_mask<<<(NN * CC / 4) / 256, 256, 0, stream>>>(maskW, gid, x, Mo, xm);
    k_pertadj<<<1024, 256, 0, stream>>>(pertW, pertB, gid, colcnt, coljs, padj, padjbits);

    // layer 0
    k_gemm_dual<<<256, 256, 0, stream>>>(x, xm, w0, Z, Zthi, Ztlo, 256, 0, 1, 0);
    k_spmm_gather<<<NN / 2, 256, 0, stream>>>(rowptr, csrcol, Z, S);
    k_mfma_spmm<<<512, 256, 0, stream>>>(padjbits, Zthi, Ztlo, Sp);
    // layer 1
    k_gemm_dual<<<256, 256, 0, stream>>>(S, Sp, w1, Z, Zthi, Ztlo, 128, 1, 8, PS);
    k_spmm_gather<<<NN / 2, 256, 0, stream>>>(rowptr, csrcol, Z, S);
    k_mfma_spmm<<<512, 256, 0, stream>>>(padjbits, Zthi, Ztlo, Sp);
    // layer 2
    k_gemm_dual<<<256, 256, 0, stream>>>(S, Sp, w2, Z, Zthi, Ztlo, 128, 1, 8, PS);
    k_spmm_gather<<<NN / 2, 256, 0, stream>>>(rowptr, csrcol, Z, S);
    k_mfma_spmm<<<512, 256, 0, stream>>>(padjbits, Zthi, Ztlo, Sp);
    // pools
    k_pool2<<<64, 256, 0, stream>>>(S, Sp, mlpW, mlpb, pred, augp, PS);
}